// Round 7
// baseline (406.728 us; speedup 1.0000x reference)
//
#include <hip/hip_runtime.h>
#include <math.h>

#define XS 512
#define YS 512
#define WDIM 256
#define NCELLS (XS * YS)          // 262144
#define K1_BLOCKS 2048
#define K1_THREADS 256            // 4 waves/block
#define NWAVES (K1_BLOCKS * (K1_THREADS / 64))  // 8192
#define CH 4                      // cells per wave per iteration (4 KB)
#define NITERS (NCELLS / (NWAVES * CH))         // 8
#define NSLOTS 32                 // atomic sink slots
#define SLOT_STRIDE 16            // u64s per slot stride = 128 B (one cacheline)

typedef float vfloat4 __attribute__((ext_vector_type(4)));

// ---------------------------------------------------------------------------
// DIAGNOSTIC (this round only): in-situ streaming-read probe.
// Ledger: every k1 lever (reduction shape, atomic sink, NT, depth, grid
// frontier) is neutral; k1's own counters are invisible (top-5 = harness
// fills). This kernel measures what a PERFECT m13-style grid-stride float4
// read of 256 MB costs in this exact environment (behind the 1-GiB dirty
// poison fill). It reads ws poison (not W) to avoid any cache coupling with
// k1. dur_us delta vs R6's 340.3 = T_stream:
//   ~45-55us  -> reads can stream at ~6TB/s here; k1 is fixable; restructure.
//   ~110-140  -> environmental read ceiling ~2TB/s; k1 already at floor.
//   <20       -> timing model of dur_us itself is wrong.
// ---------------------------------------------------------------------------
#define PROBE_N (268435456 / 16)  // 16.78M float4s = 256 MB
__global__ __launch_bounds__(256) void stream_probe_kernel(
    const vfloat4* __restrict__ src, float* __restrict__ dst) {
  const int gtid = blockIdx.x * 256 + threadIdx.x;
  const int nthreads = K1_BLOCKS * 256;  // 524288 -> 32 iters/thread
  vfloat4 acc = {0.0f, 0.0f, 0.0f, 0.0f};
#pragma unroll 4
  for (int i = gtid; i < PROBE_N; i += nthreads) {
    const vfloat4 v = src[i];
    acc.x += v.x; acc.y += v.y; acc.z += v.z; acc.w += v.w;
  }
  dst[gtid] = acc.x + acc.y + acc.z + acc.w;  // DCE guard; value unused
}

// Kernel 1: per-cell squared L2 distance, argmin. BYTE-IDENTICAL to R6
// (ledger anchor): butterfly argmin, NT loads, 1-deep prefetch, grid-stride
// frontier, 32-slot atomic sink.
__global__ __launch_bounds__(K1_THREADS) void som_dist_kernel(
    const float* __restrict__ x,
    const float* __restrict__ W,
    unsigned long long* __restrict__ ws) {
  const int lane = threadIdx.x & 63;
  const int waveInBlock = threadIdx.x >> 6;
  const int gw = blockIdx.x * (K1_THREADS / 64) + waveInBlock;

  const vfloat4 xv = ((const vfloat4*)x)[lane];

  float bestD = 3.4e38f;
  int bestI = 0;

  const int r3 = lane & 3;   // cell-in-batch this lane owns after the butterfly
  const bool b0 = (lane & 1) != 0;
  const bool b1 = (lane & 2) != 0;

  vfloat4 buf[2][CH];  // ping-pong row data; indices static after full unroll

  {
    const vfloat4* p0 = (const vfloat4*)(W + (size_t)(gw * CH) * WDIM) + lane;
#pragma unroll
    for (int r = 0; r < CH; ++r)
      buf[0][r] = __builtin_nontemporal_load(p0 + r * (WDIM / 4));
  }

#pragma unroll
  for (int it = 0; it < NITERS; ++it) {
    if (it < NITERS - 1) {
      const vfloat4* pn =
          (const vfloat4*)(W + ((size_t)(it + 1) * (NWAVES * CH) + (size_t)gw * CH) * WDIM) +
          lane;
#pragma unroll
      for (int r = 0; r < CH; ++r)
        buf[(it + 1) & 1][r] = __builtin_nontemporal_load(pn + r * (WDIM / 4));
    }

    const int cb = it * (NWAVES * CH) + gw * CH;

    float s0, s1, s2, s3;
    {
      const vfloat4 w0 = buf[it & 1][0];
      const vfloat4 w1 = buf[it & 1][1];
      const vfloat4 w2 = buf[it & 1][2];
      const vfloat4 w3 = buf[it & 1][3];
      float d;
      d = xv.x - w0.x; s0  = d * d;
      d = xv.y - w0.y; s0 += d * d;
      d = xv.z - w0.z; s0 += d * d;
      d = xv.w - w0.w; s0 += d * d;

      d = xv.x - w1.x; s1  = d * d;
      d = xv.y - w1.y; s1 += d * d;
      d = xv.z - w1.z; s1 += d * d;
      d = xv.w - w1.w; s1 += d * d;

      d = xv.x - w2.x; s2  = d * d;
      d = xv.y - w2.y; s2 += d * d;
      d = xv.z - w2.z; s2 += d * d;
      d = xv.w - w2.w; s2 += d * d;

      d = xv.x - w3.x; s3  = d * d;
      d = xv.y - w3.y; s3 += d * d;
      d = xv.z - w3.z; s3 += d * d;
      d = xv.w - w3.w; s3 += d * d;
    }

    float keepA = b0 ? s1 : s0;
    float sendA = b0 ? s0 : s1;
    float t0 = keepA + __shfl_xor(sendA, 1, 64);
    float keepB = b0 ? s3 : s2;
    float sendB = b0 ? s2 : s3;
    float t1 = keepB + __shfl_xor(sendB, 1, 64);

    float keepC = b1 ? t1 : t0;
    float sendC = b1 ? t0 : t1;
    float v = keepC + __shfl_xor(sendC, 2, 64);

    v += __shfl_xor(v, 4, 64);
    v += __shfl_xor(v, 8, 64);
    v += __shfl_xor(v, 16, 64);
    v += __shfl_xor(v, 32, 64);

    if (v < bestD) { bestD = v; bestI = cb + r3; }
  }

  unsigned long long packed =
      ((unsigned long long)__float_as_uint(bestD) << 32) | (unsigned int)bestI;

#pragma unroll
  for (int off = 32; off > 0; off >>= 1) {
    const unsigned long long o = __shfl_xor(packed, off, 64);
    packed = (o < packed) ? o : packed;
  }

  __shared__ unsigned long long sbest[K1_THREADS / 64];
  if (lane == 0) sbest[waveInBlock] = packed;
  __syncthreads();
  if (threadIdx.x == 0) {
    unsigned long long m = sbest[0];
#pragma unroll
    for (int i = 1; i < K1_THREADS / 64; ++i) {
      const unsigned long long v2 = sbest[i];
      m = (v2 < m) ? v2 : m;
    }
    atomicMin(ws + (blockIdx.x & (NSLOTS - 1)) * SLOT_STRIDE, m);
  }
}

// Kernel 2: reduce the 32 slots (L2-hot), write h; block 0 appends wx, wy.
__global__ __launch_bounds__(256) void som_h_kernel(
    const unsigned long long* __restrict__ ws,
    const int* __restrict__ time_step,
    float* __restrict__ out) {
  const int t = threadIdx.x;
  const int lane = t & 63;

  unsigned long long v = ws[(lane & (NSLOTS - 1)) * SLOT_STRIDE];
#pragma unroll
  for (int off = 1; off < 32; off <<= 1) {
    const unsigned long long o = __shfl_xor(v, off, 64);
    v = (o < v) ? o : v;
  }

  const int flat = (int)(v & 0xFFFFFFFFULL);
  const int wx = flat >> 9;       // flat / 512
  const int wy = flat & (YS - 1); // flat % 512

  const float ts = (float)(*time_step);
  const float TIME_CONST = 1442.6950408889634f;  // 1000 / ln(2)
  const float decay = 2.0f * expf(-ts / TIME_CONST);
  const float denom = 2.0f * decay * decay;
  const float inv = -1.0f / denom;

  const int e = blockIdx.x * 1024 + t * 4;
  const int i = e >> 9;
  const int j0 = e & (YS - 1);
  const float di = (float)(i - wx);
  const float di2 = di * di;

  const float d0 = (float)(j0 + 0 - wy);
  const float d1 = (float)(j0 + 1 - wy);
  const float d2 = (float)(j0 + 2 - wy);
  const float d3 = (float)(j0 + 3 - wy);
  vfloat4 r;
  r.x = expf((di2 + d0 * d0) * inv);
  r.y = expf((di2 + d1 * d1) * inv);
  r.z = expf((di2 + d2 * d2) * inv);
  r.w = expf((di2 + d3 * d3) * inv);
  ((vfloat4*)out)[e >> 2] = r;

  if (blockIdx.x == 0 && t == 0) {
    out[NCELLS] = (float)wx;      // output order: h, wx, wy
    out[NCELLS + 1] = (float)wy;
  }
}

extern "C" void kernel_launch(void* const* d_in, const int* in_sizes, int n_in,
                              void* d_out, int out_size, void* d_ws, size_t ws_size,
                              hipStream_t stream) {
  const float* x = (const float*)d_in[0];
  const float* W = (const float*)d_in[1];
  const int* ts = (const int*)d_in[2];
  float* out = (float*)d_out;
  unsigned long long* ws = (unsigned long long*)d_ws;
  char* wsBytes = (char*)d_ws;

  // Init the 32 strided atomic slots (4 KB) to u64-max.
  (void)hipMemsetAsync(ws, 0xFF, NSLOTS * SLOT_STRIDE * 8, stream);

  // Diagnostic probe: stream-read 256 MB of ws poison (upper half of the
  // 1-GiB workspace), write 2 MB of sums at +16 KB. No overlap with slots.
  stream_probe_kernel<<<K1_BLOCKS, 256, 0, stream>>>(
      (const vfloat4*)(wsBytes + (512ull << 20)),
      (float*)(wsBytes + (16ull << 10)));

  som_dist_kernel<<<K1_BLOCKS, K1_THREADS, 0, stream>>>(x, W, ws);
  som_h_kernel<<<NCELLS / 1024, 256, 0, stream>>>(ws, ts, out);
}

// Round 9
// 375.029 us; speedup vs baseline: 1.0845x; 1.0845x over previous
//
#include <hip/hip_runtime.h>
#include <math.h>

#define XS 512
#define YS 512
#define WDIM 256
#define NCELLS (XS * YS)          // 262144
#define K1_BLOCKS 2048
#define K1_THREADS 256            // 4 waves/block
#define NTHREADS (K1_BLOCKS * K1_THREADS)       // 524288
#define NWAVES (NTHREADS / 64)                  // 8192
#define K1_ITERS 32               // 32 float4 loads/thread covers all of W
#define NSLOTS 32                 // atomic sink slots
#define SLOT_STRIDE 16            // u64s per slot stride = 128 B (one cacheline)

typedef float vfloat4 __attribute__((ext_vector_type(4)));

// Kernel 1: per-cell squared L2 distance, argmin — PROBE-SHAPED.
// R7's in-situ probe streamed 256 MB at 3.86 TB/s (66 us) in this exact
// environment, while every LDS/shuffle-interleaved k1 variant ran 268 MB at
// 1.67 TB/s (~160 us). Falsified so far: shuffle density (1.2-6/KB all
// equal), atomic sink, grid frontier, per-stream depth; NT ~ -15us.
// This k1 IS the probe: thread-contiguous grid-stride float4 loads, normal
// (non-NT) loads, consumption is lane-local FMA into 32 independent
// accumulators — ZERO cross-lane ops in the load stream. Identity making
// this possible: for f = gtid + it*NTHREADS, cell(f) = f>>6 = w + it*8192
// (wave-uniform), lane = k-slice. All reduction deferred to one epilogue:
// 5 value-halving butterfly stages (31 shuffles) fold 32 accs x 64 lanes ->
// lane l holds full distance of cell w + (l&31)*8192; then packed-u64
// argmin as before.
__global__ __launch_bounds__(K1_THREADS) void som_dist_kernel(
    const float* __restrict__ x,
    const float* __restrict__ W,
    unsigned long long* __restrict__ ws) {
  const int tid = threadIdx.x;
  const int lane = tid & 63;
  const int waveInBlock = tid >> 6;
  const int gtid = blockIdx.x * K1_THREADS + tid;
  const int w = gtid >> 6;  // global wave id = base cell

  const vfloat4 xv = ((const vfloat4*)x)[lane];
  const vfloat4* __restrict__ W4 = (const vfloat4*)W;

  // ---- probe-identical load stream: 32 independent loads, lane-local FMA ----
  float acc[K1_ITERS];
#pragma unroll
  for (int it = 0; it < K1_ITERS; ++it) {
    const vfloat4 v = W4[(size_t)gtid + (size_t)it * NTHREADS];
    const float dx = xv.x - v.x;
    const float dy = xv.y - v.y;
    const float dz = xv.z - v.z;
    const float dw = xv.w - v.w;
    acc[it] = dx * dx + dy * dy + dz * dz + dw * dw;
  }

  // ---- epilogue: fold 32 accs x 64 lanes with 31+1 shuffles ----
  // After stage s (mask 2^(s-1)), acc[j] = cell it = j*2^s + (lane & (2^s-1)),
  // summed over lane bits 0..s-1. After 5 stages + mask-32 fold: lane l holds
  // the full 64-lane sum for it = (l & 31).
  const bool b0 = (lane & 1) != 0;
  const bool b1 = (lane & 2) != 0;
  const bool b2 = (lane & 4) != 0;
  const bool b3 = (lane & 8) != 0;
  const bool b4 = (lane & 16) != 0;

#pragma unroll
  for (int j = 0; j < 16; ++j) {
    const float keep = b0 ? acc[2 * j + 1] : acc[2 * j];
    const float send = b0 ? acc[2 * j] : acc[2 * j + 1];
    acc[j] = keep + __shfl_xor(send, 1, 64);
  }
#pragma unroll
  for (int j = 0; j < 8; ++j) {
    const float keep = b1 ? acc[2 * j + 1] : acc[2 * j];
    const float send = b1 ? acc[2 * j] : acc[2 * j + 1];
    acc[j] = keep + __shfl_xor(send, 2, 64);
  }
#pragma unroll
  for (int j = 0; j < 4; ++j) {
    const float keep = b2 ? acc[2 * j + 1] : acc[2 * j];
    const float send = b2 ? acc[2 * j] : acc[2 * j + 1];
    acc[j] = keep + __shfl_xor(send, 4, 64);
  }
#pragma unroll
  for (int j = 0; j < 2; ++j) {
    const float keep = b3 ? acc[2 * j + 1] : acc[2 * j];
    const float send = b3 ? acc[2 * j] : acc[2 * j + 1];
    acc[j] = keep + __shfl_xor(send, 8, 64);
  }
  {
    const float keep = b4 ? acc[1] : acc[0];
    const float send = b4 ? acc[0] : acc[1];
    acc[0] = keep + __shfl_xor(send, 16, 64);
  }
  const float v = acc[0] + __shfl_xor(acc[0], 32, 64);  // full 64-lane sum

  // lane l owns cell w + (l&31)*8192 (half-waves duplicate: harmless for min)
  const int cell = w + (lane & 31) * NWAVES;

  // fp32 dist (>=0) bit pattern is order-monotone as u32; index in low 32.
  // Packed u64 min => lowest distance, ties broken by lowest index.
  unsigned long long packed =
      ((unsigned long long)__float_as_uint(v) << 32) | (unsigned int)cell;

#pragma unroll
  for (int off = 32; off > 0; off >>= 1) {
    const unsigned long long o = __shfl_xor(packed, off, 64);
    packed = (o < packed) ? o : packed;
  }

  __shared__ unsigned long long sbest[K1_THREADS / 64];
  if (lane == 0) sbest[waveInBlock] = packed;
  __syncthreads();
  if (tid == 0) {
    unsigned long long m = sbest[0];
#pragma unroll
    for (int i = 1; i < K1_THREADS / 64; ++i) {
      const unsigned long long v2 = sbest[i];
      m = (v2 < m) ? v2 : m;
    }
    // 32 cacheline-strided slots (measured neutral vs 1 slot, kept: harmless)
    atomicMin(ws + (blockIdx.x & (NSLOTS - 1)) * SLOT_STRIDE, m);
  }
}

// Kernel 2: reduce the 32 slots (L2-hot), write h; block 0 appends wx, wy.
__global__ __launch_bounds__(256) void som_h_kernel(
    const unsigned long long* __restrict__ ws,
    const int* __restrict__ time_step,
    float* __restrict__ out) {
  const int t = threadIdx.x;
  const int lane = t & 63;

  // lanes 0-31 and 32-63 each load all 32 slots; 5-step butterfly within each
  // 32-lane half leaves the global min in EVERY lane.
  unsigned long long v = ws[(lane & (NSLOTS - 1)) * SLOT_STRIDE];
#pragma unroll
  for (int off = 1; off < 32; off <<= 1) {
    const unsigned long long o = __shfl_xor(v, off, 64);
    v = (o < v) ? o : v;
  }

  const int flat = (int)(v & 0xFFFFFFFFULL);
  const int wx = flat >> 9;       // flat / 512
  const int wy = flat & (YS - 1); // flat % 512

  // decay = SIGMA * exp(-t / (1000/ln(SIGMA))), SIGMA = 2
  const float ts = (float)(*time_step);
  const float TIME_CONST = 1442.6950408889634f;  // 1000 / ln(2)
  const float decay = 2.0f * expf(-ts / TIME_CONST);
  const float denom = 2.0f * decay * decay;
  const float inv = -1.0f / denom;

  // h[i][j] = exp(-((i-wx)^2 + (j-wy)^2) / denom); one float4 per thread
  const int e = blockIdx.x * 1024 + t * 4;
  const int i = e >> 9;
  const int j0 = e & (YS - 1);
  const float di = (float)(i - wx);
  const float di2 = di * di;

  const float d0 = (float)(j0 + 0 - wy);
  const float d1 = (float)(j0 + 1 - wy);
  const float d2 = (float)(j0 + 2 - wy);
  const float d3 = (float)(j0 + 3 - wy);
  vfloat4 r;
  r.x = expf((di2 + d0 * d0) * inv);
  r.y = expf((di2 + d1 * d1) * inv);
  r.z = expf((di2 + d2 * d2) * inv);
  r.w = expf((di2 + d3 * d3) * inv);
  ((vfloat4*)out)[e >> 2] = r;

  if (blockIdx.x == 0 && t == 0) {
    out[NCELLS] = (float)wx;      // output order: h, wx, wy
    out[NCELLS + 1] = (float)wy;
  }
}

extern "C" void kernel_launch(void* const* d_in, const int* in_sizes, int n_in,
                              void* d_out, int out_size, void* d_ws, size_t ws_size,
                              hipStream_t stream) {
  const float* x = (const float*)d_in[0];
  const float* W = (const float*)d_in[1];
  const int* ts = (const int*)d_in[2];
  float* out = (float*)d_out;
  unsigned long long* ws = (unsigned long long*)d_ws;

  // Init all 32 strided slots to u64-max so atomicMin never sees poison.
  (void)hipMemsetAsync(ws, 0xFF, NSLOTS * SLOT_STRIDE * 8, stream);
  som_dist_kernel<<<K1_BLOCKS, K1_THREADS, 0, stream>>>(x, W, ws);
  som_h_kernel<<<NCELLS / 1024, 256, 0, stream>>>(ws, ts, out);
}

// Round 10
// 349.760 us; speedup vs baseline: 1.1629x; 1.0722x over previous
//
#include <hip/hip_runtime.h>
#include <math.h>

#define XS 512
#define YS 512
#define WDIM 256
#define NCELLS (XS * YS)          // 262144
#define K1_BLOCKS 2048
#define K1_THREADS 256            // 4 waves/block
#define NTHREADS (K1_BLOCKS * K1_THREADS)       // 524288
#define NWAVES (NTHREADS / 64)                  // 8192
#define NCHUNKS 4
#define CPER 8                    // loads per chunk; 4*8=32 covers all of W
#define NSLOTS 32                 // atomic sink slots
#define SLOT_STRIDE 16            // u64s per slot stride = 128 B (one cacheline)

typedef float vfloat4 __attribute__((ext_vector_type(4)));

// Kernel 1: per-cell squared L2 distance, argmin — probe-shaped, LEAN.
// Ledger: 6 structural k1 variants all read W at 1.4-1.7 TB/s while the
// SAME-shaped probe read ws at 3.86 TB/s (R7), even cleaning L3 first.
// R9 (acc[32] full unroll, NT dropped) regressed to ~195us: VGPR bloat +
// lost the NT lever. This version = probe register profile (chunked acc[8],
// rolling 8-load windows, ~50 VGPR) + NT restored + deferred epilogue
// (10 shuffles per 8KB chunk). It is the last structural variant: if this
// too lands at k1~160us, the W-buffer allocation property (TLB/MTYPE) is
// the cap and R5/R6's 339us is the environmental roofline.
// Identity: f = gtid + it*NTHREADS -> cell f>>6 = w + it*8192, wave-uniform;
// lane = k-slice. Chunk c epilogue: 3 butterfly stages (masks 1,2,4) fold
// acc[0..7] -> lane holds cell it = c*8 + (lane&7); folds 8,16,32 complete
// the 64-lane sum (8-lane duplicate groups agree bit-exactly).
__global__ __launch_bounds__(K1_THREADS) void som_dist_kernel(
    const float* __restrict__ x,
    const float* __restrict__ W,
    unsigned long long* __restrict__ ws) {
  const int tid = threadIdx.x;
  const int lane = tid & 63;
  const int waveInBlock = tid >> 6;
  const int gtid = blockIdx.x * K1_THREADS + tid;
  const int w = gtid >> 6;  // global wave id = base cell

  const vfloat4 xv = ((const vfloat4*)x)[lane];
  const vfloat4* __restrict__ W4 = (const vfloat4*)W;

  float bestD = 3.4e38f;
  int bestI = 0;

  const bool b0 = (lane & 1) != 0;
  const bool b1 = (lane & 2) != 0;
  const bool b2 = (lane & 4) != 0;
  const int r7 = lane & 7;

#pragma unroll
  for (int c = 0; c < NCHUNKS; ++c) {
    float acc[CPER];
    // 8 independent NT loads (8 KB/wave in flight), lane-local FMA only
#pragma unroll
    for (int j = 0; j < CPER; ++j) {
      const vfloat4 v = __builtin_nontemporal_load(
          W4 + (size_t)gtid + (size_t)(c * CPER + j) * NTHREADS);
      const float dx = xv.x - v.x;
      const float dy = xv.y - v.y;
      const float dz = xv.z - v.z;
      const float dw = xv.w - v.w;
      acc[j] = dx * dx + dy * dy + dz * dz + dw * dw;
    }

    // stage mask=1: 8 -> 4 (cell LSB = lane bit0)
#pragma unroll
    for (int j = 0; j < 4; ++j) {
      const float keep = b0 ? acc[2 * j + 1] : acc[2 * j];
      const float send = b0 ? acc[2 * j] : acc[2 * j + 1];
      acc[j] = keep + __shfl_xor(send, 1, 64);
    }
    // stage mask=2: 4 -> 2 (cell bit1 = lane bit1)
#pragma unroll
    for (int j = 0; j < 2; ++j) {
      const float keep = b1 ? acc[2 * j + 1] : acc[2 * j];
      const float send = b1 ? acc[2 * j] : acc[2 * j + 1];
      acc[j] = keep + __shfl_xor(send, 2, 64);
    }
    // stage mask=4: 2 -> 1 (cell bit2 = lane bit2)
    {
      const float keep = b2 ? acc[1] : acc[0];
      const float send = b2 ? acc[0] : acc[1];
      acc[0] = keep + __shfl_xor(send, 4, 64);
    }
    // fold lane bits 3..5: full 64-lane sum for cell w + (c*8 + r7)*8192
    float v = acc[0];
    v += __shfl_xor(v, 8, 64);
    v += __shfl_xor(v, 16, 64);
    v += __shfl_xor(v, 32, 64);

    // strict <: per-lane cell index increases with c => lowest index on ties
    if (v < bestD) { bestD = v; bestI = w + (c * CPER + r7) * NWAVES; }
  }

  // fp32 dist (>=0) bit pattern is order-monotone as u32; index in low 32.
  // Packed u64 min => lowest distance, ties broken by lowest index.
  unsigned long long packed =
      ((unsigned long long)__float_as_uint(bestD) << 32) | (unsigned int)bestI;

#pragma unroll
  for (int off = 32; off > 0; off >>= 1) {
    const unsigned long long o = __shfl_xor(packed, off, 64);
    packed = (o < packed) ? o : packed;
  }

  __shared__ unsigned long long sbest[K1_THREADS / 64];
  if (lane == 0) sbest[waveInBlock] = packed;
  __syncthreads();
  if (tid == 0) {
    unsigned long long m = sbest[0];
#pragma unroll
    for (int i = 1; i < K1_THREADS / 64; ++i) {
      const unsigned long long v2 = sbest[i];
      m = (v2 < m) ? v2 : m;
    }
    // 32 cacheline-strided slots (measured neutral vs 1 slot, kept: harmless)
    atomicMin(ws + (blockIdx.x & (NSLOTS - 1)) * SLOT_STRIDE, m);
  }
}

// Kernel 2: reduce the 32 slots (L2-hot), write h; block 0 appends wx, wy.
__global__ __launch_bounds__(256) void som_h_kernel(
    const unsigned long long* __restrict__ ws,
    const int* __restrict__ time_step,
    float* __restrict__ out) {
  const int t = threadIdx.x;
  const int lane = t & 63;

  // lanes 0-31 and 32-63 each load all 32 slots; 5-step butterfly within each
  // 32-lane half leaves the global min in EVERY lane.
  unsigned long long v = ws[(lane & (NSLOTS - 1)) * SLOT_STRIDE];
#pragma unroll
  for (int off = 1; off < 32; off <<= 1) {
    const unsigned long long o = __shfl_xor(v, off, 64);
    v = (o < v) ? o : v;
  }

  const int flat = (int)(v & 0xFFFFFFFFULL);
  const int wx = flat >> 9;       // flat / 512
  const int wy = flat & (YS - 1); // flat % 512

  // decay = SIGMA * exp(-t / (1000/ln(SIGMA))), SIGMA = 2
  const float ts = (float)(*time_step);
  const float TIME_CONST = 1442.6950408889634f;  // 1000 / ln(2)
  const float decay = 2.0f * expf(-ts / TIME_CONST);
  const float denom = 2.0f * decay * decay;
  const float inv = -1.0f / denom;

  // h[i][j] = exp(-((i-wx)^2 + (j-wy)^2) / denom); one float4 per thread
  const int e = blockIdx.x * 1024 + t * 4;
  const int i = e >> 9;
  const int j0 = e & (YS - 1);
  const float di = (float)(i - wx);
  const float di2 = di * di;

  const float d0 = (float)(j0 + 0 - wy);
  const float d1 = (float)(j0 + 1 - wy);
  const float d2 = (float)(j0 + 2 - wy);
  const float d3 = (float)(j0 + 3 - wy);
  vfloat4 r;
  r.x = expf((di2 + d0 * d0) * inv);
  r.y = expf((di2 + d1 * d1) * inv);
  r.z = expf((di2 + d2 * d2) * inv);
  r.w = expf((di2 + d3 * d3) * inv);
  ((vfloat4*)out)[e >> 2] = r;

  if (blockIdx.x == 0 && t == 0) {
    out[NCELLS] = (float)wx;      // output order: h, wx, wy
    out[NCELLS + 1] = (float)wy;
  }
}

extern "C" void kernel_launch(void* const* d_in, const int* in_sizes, int n_in,
                              void* d_out, int out_size, void* d_ws, size_t ws_size,
                              hipStream_t stream) {
  const float* x = (const float*)d_in[0];
  const float* W = (const float*)d_in[1];
  const int* ts = (const int*)d_in[2];
  float* out = (float*)d_out;
  unsigned long long* ws = (unsigned long long*)d_ws;

  // Init all 32 strided slots to u64-max so atomicMin never sees poison.
  (void)hipMemsetAsync(ws, 0xFF, NSLOTS * SLOT_STRIDE * 8, stream);
  som_dist_kernel<<<K1_BLOCKS, K1_THREADS, 0, stream>>>(x, W, ws);
  som_h_kernel<<<NCELLS / 1024, 256, 0, stream>>>(ws, ts, out);
}

// Round 11
// 340.355 us; speedup vs baseline: 1.1950x; 1.0276x over previous
//
#include <hip/hip_runtime.h>
#include <math.h>

#define XS 512
#define YS 512
#define WDIM 256
#define NCELLS (XS * YS)          // 262144
#define K1_BLOCKS 2048
#define K1_THREADS 256            // 4 waves/block, 32 cells/wave
#define NSLOTS 32                 // atomic sink slots
#define SLOT_STRIDE 16            // u64s per slot stride = 128 B (one cacheline)

typedef float vfloat4 __attribute__((ext_vector_type(4)));

// Kernel 1: per-cell squared L2 distance, argmin. SESSION-BEST (R5: 339.2us),
// restored as the final artifact.
// Session ledger (7 structural variants, all ref-passing):
//   serial+NT 347.8 | butterfly,noNT 363.0 | +32slot sink 362.6 |
//   THIS (NT+8deep) 339.2 | +grid-frontier 340.3 | probe-shape,noNT 375.0 |
//   lean-probe+NT 349.8
// In-situ probe (R7): identical-shape read of ws streams at 3.86 TB/s, while
// every W-read caps at ~1.7 TB/s regardless of structure => the cap is an
// allocation-level property of the input W buffer (page/MTYPE/interleave),
// not kernel-controllable. Environmental roofline:
//   161 (harness 1GiB ws poison fill) + ~157 (268MB W @ 1.7TB/s)
//   + ~10 (k2) + ~10 (gaps) ~= 339us = this kernel's measurement.
__global__ __launch_bounds__(K1_THREADS) void som_dist_kernel(
    const float* __restrict__ x,
    const float* __restrict__ W,
    unsigned long long* __restrict__ ws) {
  const int lane = threadIdx.x & 63;
  const int waveInBlock = threadIdx.x >> 6;
  const int gw = blockIdx.x * (K1_THREADS / 64) + waveInBlock;

  const vfloat4 xv = ((const vfloat4*)x)[lane];

  float bestD = 3.4e38f;
  int bestI = 0;

  const int base = gw * 32;  // 32 consecutive cells per wave, 4 batches of 8
  const int r7 = lane & 7;   // cell-in-batch this lane owns after the butterfly

  const bool b0 = (lane & 1) != 0;
  const bool b1 = (lane & 2) != 0;
  const bool b2 = (lane & 4) != 0;

  vfloat4 buf[2][8];  // double-buffered row data; all indices static after unroll

  {
    const vfloat4* p0 = (const vfloat4*)(W + (size_t)base * WDIM) + lane;
#pragma unroll
    for (int r = 0; r < 8; ++r)
      buf[0][r] = __builtin_nontemporal_load(p0 + r * (WDIM / 4));
  }

#pragma unroll
  for (int b = 0; b < 4; ++b) {
    // prefetch next 8 rows (8 KB) while reducing the current batch
    if (b < 3) {
      const vfloat4* pn =
          (const vfloat4*)(W + (size_t)(base + (b + 1) * 8) * WDIM) + lane;
#pragma unroll
      for (int r = 0; r < 8; ++r)
        buf[(b + 1) & 1][r] = __builtin_nontemporal_load(pn + r * (WDIM / 4));
    }

    const int cb = base + b * 8;
    float s[8];
#pragma unroll
    for (int r = 0; r < 8; ++r) {
      const vfloat4 wv = buf[b & 1][r];
      const float dx = xv.x - wv.x;
      const float dy = xv.y - wv.y;
      const float dz = xv.z - wv.z;
      const float dw = xv.w - wv.w;
      s[r] = dx * dx + dy * dy + dz * dz + dw * dw;
    }

    // value-halving butterfly: 8 partials -> 1 value/lane, cell = cb + (lane&7)
    // stage mask=1: pairs (0,1)(2,3)(4,5)(6,7); lane bit0 picks kept cell
    float t0, t1, t2, t3;
    {
      float k, sd;
      k = b0 ? s[1] : s[0]; sd = b0 ? s[0] : s[1];
      t0 = k + __shfl_xor(sd, 1, 64);    // cell cb + 0 + b0 (partial over 2 lanes)
      k = b0 ? s[3] : s[2]; sd = b0 ? s[2] : s[3];
      t1 = k + __shfl_xor(sd, 1, 64);    // cell cb + 2 + b0
      k = b0 ? s[5] : s[4]; sd = b0 ? s[4] : s[5];
      t2 = k + __shfl_xor(sd, 1, 64);    // cell cb + 4 + b0
      k = b0 ? s[7] : s[6]; sd = b0 ? s[6] : s[7];
      t3 = k + __shfl_xor(sd, 1, 64);    // cell cb + 6 + b0
    }
    // stage mask=2: lane bit1 picks t-pair member
    float u0, u1;
    {
      float k, sd;
      k = b1 ? t1 : t0; sd = b1 ? t0 : t1;
      u0 = k + __shfl_xor(sd, 2, 64);    // cell cb + 2*b1 + b0
      k = b1 ? t3 : t2; sd = b1 ? t2 : t3;
      u1 = k + __shfl_xor(sd, 2, 64);    // cell cb + 4 + 2*b1 + b0
    }
    // stage mask=4: lane bit2 picks u0 vs u1
    float v;
    {
      const float k = b2 ? u1 : u0;
      const float sd = b2 ? u0 : u1;
      v = k + __shfl_xor(sd, 4, 64);     // cell cb + (lane&7), 1/8 of sum
    }
    // fold the 8 duplicate lane-groups (lane bits 3..5)
    v += __shfl_xor(v, 8, 64);
    v += __shfl_xor(v, 16, 64);
    v += __shfl_xor(v, 32, 64);

    // strict < keeps the lowest index on ties within this lane's residue class
    if (v < bestD) { bestD = v; bestI = cb + r7; }
  }

  // fp32 dist (>=0) bit pattern is order-monotone as u32; index in low 32.
  // Packed u64 min => lowest distance, ties broken by lowest index.
  unsigned long long packed =
      ((unsigned long long)__float_as_uint(bestD) << 32) | (unsigned int)bestI;

  // wave-level min across the 64 per-residue candidates
#pragma unroll
  for (int off = 32; off > 0; off >>= 1) {
    const unsigned long long o = __shfl_xor(packed, off, 64);
    packed = (o < packed) ? o : packed;
  }

  __shared__ unsigned long long sbest[K1_THREADS / 64];
  if (lane == 0) sbest[waveInBlock] = packed;
  __syncthreads();
  if (threadIdx.x == 0) {
    unsigned long long m = sbest[0];
#pragma unroll
    for (int i = 1; i < K1_THREADS / 64; ++i) {
      const unsigned long long v2 = sbest[i];
      m = (v2 < m) ? v2 : m;
    }
    // 32 cacheline-strided slots (measured neutral vs 1 slot, kept: harmless)
    atomicMin(ws + (blockIdx.x & (NSLOTS - 1)) * SLOT_STRIDE, m);
  }
}

// Kernel 2: reduce the 32 slots (L2-hot), write h; block 0 appends wx, wy.
__global__ __launch_bounds__(256) void som_h_kernel(
    const unsigned long long* __restrict__ ws,
    const int* __restrict__ time_step,
    float* __restrict__ out) {
  const int t = threadIdx.x;
  const int lane = t & 63;

  // lanes 0-31 and 32-63 each load all 32 slots; 5-step butterfly within each
  // 32-lane half leaves the global min in EVERY lane.
  unsigned long long v = ws[(lane & (NSLOTS - 1)) * SLOT_STRIDE];
#pragma unroll
  for (int off = 1; off < 32; off <<= 1) {
    const unsigned long long o = __shfl_xor(v, off, 64);
    v = (o < v) ? o : v;
  }

  const int flat = (int)(v & 0xFFFFFFFFULL);
  const int wx = flat >> 9;       // flat / 512
  const int wy = flat & (YS - 1); // flat % 512

  // decay = SIGMA * exp(-t / (1000/ln(SIGMA))), SIGMA = 2
  const float ts = (float)(*time_step);
  const float TIME_CONST = 1442.6950408889634f;  // 1000 / ln(2)
  const float decay = 2.0f * expf(-ts / TIME_CONST);
  const float denom = 2.0f * decay * decay;
  const float inv = -1.0f / denom;

  // h[i][j] = exp(-((i-wx)^2 + (j-wy)^2) / denom); one float4 per thread
  const int e = blockIdx.x * 1024 + t * 4;
  const int i = e >> 9;
  const int j0 = e & (YS - 1);
  const float di = (float)(i - wx);
  const float di2 = di * di;

  const float d0 = (float)(j0 + 0 - wy);
  const float d1 = (float)(j0 + 1 - wy);
  const float d2 = (float)(j0 + 2 - wy);
  const float d3 = (float)(j0 + 3 - wy);
  vfloat4 r;
  r.x = expf((di2 + d0 * d0) * inv);
  r.y = expf((di2 + d1 * d1) * inv);
  r.z = expf((di2 + d2 * d2) * inv);
  r.w = expf((di2 + d3 * d3) * inv);
  ((vfloat4*)out)[e >> 2] = r;

  if (blockIdx.x == 0 && t == 0) {
    out[NCELLS] = (float)wx;      // output order: h, wx, wy
    out[NCELLS + 1] = (float)wy;
  }
}

extern "C" void kernel_launch(void* const* d_in, const int* in_sizes, int n_in,
                              void* d_out, int out_size, void* d_ws, size_t ws_size,
                              hipStream_t stream) {
  const float* x = (const float*)d_in[0];
  const float* W = (const float*)d_in[1];
  const int* ts = (const int*)d_in[2];
  float* out = (float*)d_out;
  unsigned long long* ws = (unsigned long long*)d_ws;

  // Init all 32 strided slots to u64-max so atomicMin never sees poison.
  (void)hipMemsetAsync(ws, 0xFF, NSLOTS * SLOT_STRIDE * 8, stream);
  som_dist_kernel<<<K1_BLOCKS, K1_THREADS, 0, stream>>>(x, W, ws);
  som_h_kernel<<<NCELLS / 1024, 256, 0, stream>>>(ws, ts, out);
}